// Round 5
// baseline (387.465 us; speedup 1.0000x reference)
//
#include <hip/hip_runtime.h>
#include <math.h>

#define NN 100000
#define EE 1600000
#define ETOT (EE + NN)
#define NBLK 391       // ceil(NN/256)

typedef __attribute__((ext_vector_type(8))) short bf16x8;
typedef __attribute__((ext_vector_type(4))) float f32x4;

__device__ __forceinline__ unsigned short f2bf(float f) {
  unsigned int u = __float_as_uint(f);
  u = u + 0x7fffu + ((u >> 16) & 1u);  // RNE
  return (unsigned short)(u >> 16);
}

__device__ __forceinline__ float lrelu_exp(float e) {
  e = (e > 0.f) ? e : 0.2f * e;
  return __expf(e);
}

// zero the degree array (must precede the atomic count in k_gemm)
__global__ __launch_bounds__(256) void k_zero(int* __restrict__ deg) {
  int i = blockIdx.x * 256 + threadIdx.x;
  if (i < NN) deg[i] = 0;
}

// MFMA bf16 GEMM: xwb = bf16(x @ W). Block = 64 rows (4 waves x 16), N=128 full.
// Fused: per-(row,head) logits asrc/adst from the LDS output stage, AND the
// per-destination degree count (grid-stride over edges, global atomics).
__global__ __launch_bounds__(256) void k_gemm(const float* __restrict__ x,
                                              const float* __restrict__ W,
                                              const float* __restrict__ att_src,
                                              const float* __restrict__ att_dst,
                                              const int* __restrict__ ei,
                                              unsigned short* __restrict__ xwb,
                                              float* __restrict__ asrc,
                                              float* __restrict__ adst,
                                              int* __restrict__ deg) {
  __shared__ __align__(16) unsigned short lds[17408];  // Wt[128][136] bf16; reused as stage[64][128]
  __shared__ float satt[256];                          // att_src[128] ++ att_dst[128]
  int tid = threadIdx.x;
  // stage W^T (bf16) : Wt[n][k], padded row stride 136 to break bank conflicts
  for (int i = tid; i < 16384; i += 256) {
    int k = i >> 7, n = i & 127;
    lds[n * 136 + k] = f2bf(W[i]);
  }
  if (tid < 128) satt[tid] = att_src[tid];
  else satt[tid] = att_dst[tid - 128];
  __syncthreads();

  int wv = tid >> 6, lane = tid & 63;
  int m = lane & 15, q = lane >> 4;
  int r = blockIdx.x * 64 + wv * 16 + m;  // this lane's A row
  bool rok = (r < NN);

  // A fragments for all 4 k-tiles: af[kt][j] = bf16(x[r][kt*32 + q*8 + j])
  bf16x8 af[4];
#pragma unroll
  for (int kt = 0; kt < 4; kt++) {
    float4 v0 = make_float4(0.f, 0.f, 0.f, 0.f), v1 = v0;
    if (rok) {
      v0 = ((const float4*)x)[(size_t)r * 32 + kt * 8 + q * 2];
      v1 = ((const float4*)x)[(size_t)r * 32 + kt * 8 + q * 2 + 1];
    }
    af[kt][0] = (short)f2bf(v0.x); af[kt][1] = (short)f2bf(v0.y);
    af[kt][2] = (short)f2bf(v0.z); af[kt][3] = (short)f2bf(v0.w);
    af[kt][4] = (short)f2bf(v1.x); af[kt][5] = (short)f2bf(v1.y);
    af[kt][6] = (short)f2bf(v1.z); af[kt][7] = (short)f2bf(v1.w);
  }

  f32x4 acc[8];
#pragma unroll
  for (int nt = 0; nt < 8; nt++) acc[nt] = (f32x4){0.f, 0.f, 0.f, 0.f};

#pragma unroll
  for (int nt = 0; nt < 8; nt++) {
#pragma unroll
    for (int kt = 0; kt < 4; kt++) {
      bf16x8 bf = *((const bf16x8*)&lds[(nt * 16 + m) * 136 + kt * 32 + q * 8]);
      acc[nt] = __builtin_amdgcn_mfma_f32_16x16x32_bf16(af[kt], bf, acc[nt], 0, 0, 0);
    }
  }

  __syncthreads();  // all waves done reading Wt; reuse LDS as output stage
#pragma unroll
  for (int nt = 0; nt < 8; nt++)
#pragma unroll
    for (int rg = 0; rg < 4; rg++)
      lds[(wv * 16 + q * 4 + rg) * 128 + nt * 16 + m] = f2bf(acc[nt][rg]);
  __syncthreads();

  size_t base = (size_t)blockIdx.x * 16384;  // bytes; block tile is contiguous
  const size_t lim = (size_t)NN * 256;
  for (int i = tid; i < 1024; i += 256) {
    size_t off = base + (size_t)i * 16;
    if (off < lim) *((uint4*)((char*)xwb + off)) = ((const uint4*)lds)[i];
  }

  // fused logits: thread t -> (row = t>>2, head = t&3); 32 channels each from LDS
  int row = tid >> 2, h = tid & 3;
  int node = blockIdx.x * 64 + row;
  if (node < NN) {
    float ss = 0.f, sd = 0.f;
#pragma unroll
    for (int cq = 0; cq < 4; cq++) {
      uint4 u = *((const uint4*)&lds[row * 128 + h * 32 + cq * 8]);
      int cb = h * 32 + cq * 8;
      float f0 = __uint_as_float(u.x << 16), f1 = __uint_as_float(u.x & 0xffff0000u);
      float f2 = __uint_as_float(u.y << 16), f3 = __uint_as_float(u.y & 0xffff0000u);
      float f4 = __uint_as_float(u.z << 16), f5 = __uint_as_float(u.z & 0xffff0000u);
      float f6 = __uint_as_float(u.w << 16), f7 = __uint_as_float(u.w & 0xffff0000u);
      ss += f0 * satt[cb] + f1 * satt[cb + 1] + f2 * satt[cb + 2] + f3 * satt[cb + 3] +
            f4 * satt[cb + 4] + f5 * satt[cb + 5] + f6 * satt[cb + 6] + f7 * satt[cb + 7];
      sd += f0 * satt[128 + cb] + f1 * satt[128 + cb + 1] + f2 * satt[128 + cb + 2] +
            f3 * satt[128 + cb + 3] + f4 * satt[128 + cb + 4] + f5 * satt[128 + cb + 5] +
            f6 * satt[128 + cb + 6] + f7 * satt[128 + cb + 7];
    }
    asrc[(size_t)node * 4 + h] = ss;
    adst[(size_t)node * 4 + h] = sd;
  }

  // fused degree count: grid-stride over edge dst (overlaps with tail latency)
  int gs = gridDim.x * 256;
  for (int e = blockIdx.x * 256 + tid; e < EE; e += gs) {
    int d = ei[(size_t)EE + e];
    atomicAdd(&deg[d], 1);
  }
}

// scanA: per-256-node-block exclusive scan of (deg+1); local-excl -> offs, totals -> T2.
__global__ __launch_bounds__(256) void k_scanA(const int* __restrict__ deg,
                                               int* __restrict__ offs,
                                               int* __restrict__ T2) {
  __shared__ int s[256];
  int b = blockIdx.x, t = threadIdx.x;
  int n = b * 256 + t;
  int v = (n < NN) ? deg[n] + 1 : 0;  // +1 = self-loop
  s[t] = v;
  __syncthreads();
  for (int off = 1; off < 256; off <<= 1) {
    int tmp = (t >= off) ? s[t - off] : 0;
    __syncthreads();
    s[t] += tmp;
    __syncthreads();
  }
  if (n < NN) offs[n] = s[t] - v;
  if (t == 255) T2[b] = s[255];
}

// s2b: exclusive scan of the 391 block totals.
__global__ __launch_bounds__(512) void k_s2b(const int* __restrict__ T2,
                                             int* __restrict__ Base2,
                                             int* __restrict__ offs) {
  __shared__ int s[512];
  int t = threadIdx.x;
  int v = (t < NBLK) ? T2[t] : 0;
  s[t] = v;
  __syncthreads();
  for (int off = 1; off < 512; off <<= 1) {
    int tmp = (t >= off) ? s[t - off] : 0;
    __syncthreads();
    s[t] += tmp;
    __syncthreads();
  }
  Base2[t] = s[t] - v;
  if (t == 0) offs[NN] = ETOT;
}

// scanB: finalize offs, seed self-loop entry, init per-node cursor.
__global__ __launch_bounds__(256) void k_scanB(const int* __restrict__ Base2,
                                               int* __restrict__ offs,
                                               int* __restrict__ es,
                                               int* __restrict__ cur) {
  int b = blockIdx.x, t = threadIdx.x;
  int n = b * 256 + t;
  if (n < NN) {
    int o = offs[n] + Base2[b];
    offs[n] = o;
    es[o] = n;        // self-loop src first
    cur[n] = o + 1;
  }
}

// place: scatter src into each destination's CSR row via global atomic cursors.
__global__ __launch_bounds__(256) void k_place(const int* __restrict__ ei,
                                               int* __restrict__ cur,
                                               int* __restrict__ es) {
  int gs = gridDim.x * 256;
  for (int e = blockIdx.x * 256 + threadIdx.x; e < EE; e += gs) {
    int s = ei[e];
    int d = ei[(size_t)EE + e];
    int pos = atomicAdd(&cur[d], 1);
    es[pos] = s;
  }
}

// one wave per destination node: gather + on-the-fly softmax + in-register denom.
// Exp dedup: per 8-edge batch, lane l computes exp for (edge l>>3, head l&3);
// consumers fetch via __shfl(wl, q*8+h). 8 xwb gathers in flight per iter.
__global__ __launch_bounds__(256) void k_agg(const unsigned short* __restrict__ xwb,
                                             const float* __restrict__ asrc,
                                             const float* __restrict__ adst,
                                             const int* __restrict__ offs,
                                             const int* __restrict__ es,
                                             const float* __restrict__ bias,
                                             const float* __restrict__ gamma,
                                             const float* __restrict__ beta,
                                             float* __restrict__ out) {
  int lane = threadIdx.x & 63;
  int node = blockIdx.x * 4 + (threadIdx.x >> 6);
  int off0 = offs[node];
  int d = offs[node + 1] - off0;
  int h = lane >> 4;   // head for channel accumulation (c = lane*2)
  int he = lane & 3;   // head for this lane's exp duty
  int c = lane * 2;

  float4 ad4 = *((const float4*)(adst + (size_t)node * 4));
  float adh = (h & 2) ? ((h & 1) ? ad4.w : ad4.z) : ((h & 1) ? ad4.y : ad4.x);
  float ade = (he & 2) ? ((he & 1) ? ad4.w : ad4.z) : ((he & 1) ? ad4.y : ad4.x);

  const unsigned* xp = (const unsigned*)xwb + lane;
  const int* ep = es + off0;
  float ax0 = 0.f, ay0 = 0.f, ax1 = 0.f, ay1 = 0.f;
  float wsum = 0.f;

  int j = 0;
  for (; j + 8 <= d; j += 8) {
    int4 sa = *((const int4*)(ep + j));
    int4 sb = *((const int4*)(ep + j + 4));
    // lane's exp assignment: edge (lane>>3), head (lane&3); coalesced asrc read
    int se = ep[j + (lane >> 3)];
    float av = asrc[(size_t)(unsigned)se * 4u + (unsigned)he];
    unsigned u0 = xp[(unsigned)sa.x * 64u];
    unsigned u1 = xp[(unsigned)sa.y * 64u];
    unsigned u2 = xp[(unsigned)sa.z * 64u];
    unsigned u3 = xp[(unsigned)sa.w * 64u];
    unsigned u4 = xp[(unsigned)sb.x * 64u];
    unsigned u5 = xp[(unsigned)sb.y * 64u];
    unsigned u6 = xp[(unsigned)sb.z * 64u];
    unsigned u7 = xp[(unsigned)sb.w * 64u];
    float wl = lrelu_exp(av + ade);
    float w0 = __shfl(wl, 0 * 8 + h);
    float w1 = __shfl(wl, 1 * 8 + h);
    float w2 = __shfl(wl, 2 * 8 + h);
    float w3 = __shfl(wl, 3 * 8 + h);
    float w4 = __shfl(wl, 4 * 8 + h);
    float w5 = __shfl(wl, 5 * 8 + h);
    float w6 = __shfl(wl, 6 * 8 + h);
    float w7 = __shfl(wl, 7 * 8 + h);
    wsum += ((w0 + w1) + (w2 + w3)) + ((w4 + w5) + (w6 + w7));
    ax0 = fmaf(w0, __uint_as_float(u0 << 16), ax0);
    ay0 = fmaf(w0, __uint_as_float(u0 & 0xffff0000u), ay0);
    ax1 = fmaf(w1, __uint_as_float(u1 << 16), ax1);
    ay1 = fmaf(w1, __uint_as_float(u1 & 0xffff0000u), ay1);
    ax0 = fmaf(w2, __uint_as_float(u2 << 16), ax0);
    ay0 = fmaf(w2, __uint_as_float(u2 & 0xffff0000u), ay0);
    ax1 = fmaf(w3, __uint_as_float(u3 << 16), ax1);
    ay1 = fmaf(w3, __uint_as_float(u3 & 0xffff0000u), ay1);
    ax0 = fmaf(w4, __uint_as_float(u4 << 16), ax0);
    ay0 = fmaf(w4, __uint_as_float(u4 & 0xffff0000u), ay0);
    ax1 = fmaf(w5, __uint_as_float(u5 << 16), ax1);
    ay1 = fmaf(w5, __uint_as_float(u5 & 0xffff0000u), ay1);
    ax0 = fmaf(w6, __uint_as_float(u6 << 16), ax0);
    ay0 = fmaf(w6, __uint_as_float(u6 & 0xffff0000u), ay0);
    ax1 = fmaf(w7, __uint_as_float(u7 << 16), ax1);
    ay1 = fmaf(w7, __uint_as_float(u7 & 0xffff0000u), ay1);
  }
  for (; j < d; ++j) {
    int s0 = ep[j];
    float w = lrelu_exp(asrc[(size_t)(unsigned)s0 * 4u + (unsigned)h] + adh);
    wsum += w;
    unsigned u0 = xp[(unsigned)s0 * 64u];
    ax0 = fmaf(w, __uint_as_float(u0 << 16), ax0);
    ay0 = fmaf(w, __uint_as_float(u0 & 0xffff0000u), ay0);
  }
  float accx = ax0 + ax1, accy = ay0 + ay1;
  float rn = 1.f / (wsum + 1e-16f);

  float vx = accx * rn + bias[c];
  float vy = accy * rn + bias[c + 1];
  float sum = vx + vy, sq = vx * vx + vy * vy;
#pragma unroll
  for (int o = 32; o; o >>= 1) {
    sum += __shfl_xor(sum, o);
    sq += __shfl_xor(sq, o);
  }
  float mean = sum * (1.f / 128.f);
  float var = sq * (1.f / 128.f) - mean * mean;
  float rs = rsqrtf(var + 1e-5f);
  float o0 = gamma[c] * (vx - mean) * rs + beta[c];
  float o1 = gamma[c + 1] * (vy - mean) * rs + beta[c + 1];
  float2 ov; ov.x = o0; ov.y = o1;
  *((float2*)(out + (size_t)node * 128 + c)) = ov;
}

extern "C" void kernel_launch(void* const* d_in, const int* in_sizes, int n_in,
                              void* d_out, int out_size, void* d_ws, size_t ws_size,
                              hipStream_t stream) {
  const float* x = (const float*)d_in[0];
  const int* ei = (const int*)d_in[1];  // int32 per harness contract
  const float* W = (const float*)d_in[3];
  const float* att_src = (const float*)d_in[4];
  const float* att_dst = (const float*)d_in[5];
  const float* bias = (const float*)d_in[6];
  const float* gamma = (const float*)d_in[7];
  const float* beta = (const float*)d_in[8];
  float* out = (float*)d_out;

  char* p = (char*)d_ws;
  auto alloc = [&](size_t bytes) -> char* {
    char* r = p;
    p += (bytes + 255) & ~(size_t)255;
    return r;
  };
  unsigned short* xwb = (unsigned short*)alloc((size_t)NN * 128 * 2);  // 25.6 MB
  float* asrc = (float*)alloc((size_t)NN * 4 * 4);                     // 1.6 MB
  float* adst = (float*)alloc((size_t)NN * 4 * 4);                     // 1.6 MB
  int* es = (int*)alloc((size_t)ETOT * 4 + 128);                       // 6.8 MB
  int* offs = (int*)alloc((size_t)(NN + 1) * 4);
  int* deg = (int*)alloc((size_t)NN * 4);
  int* cur = (int*)alloc((size_t)NN * 4);
  int* T2 = (int*)alloc((size_t)512 * 4);
  int* Base2 = (int*)alloc((size_t)512 * 4);

  k_zero<<<NBLK, 256, 0, stream>>>(deg);
  k_gemm<<<(NN + 63) / 64, 256, 0, stream>>>(x, W, att_src, att_dst, ei, xwb, asrc, adst, deg);
  k_scanA<<<NBLK, 256, 0, stream>>>(deg, offs, T2);
  k_s2b<<<1, 512, 0, stream>>>(T2, Base2, offs);
  k_scanB<<<NBLK, 256, 0, stream>>>(Base2, offs, es, cur);
  k_place<<<1024, 256, 0, stream>>>(ei, cur, es);
  k_agg<<<NN / 4, 256, 0, stream>>>(xwb, asrc, adst, offs, es, bias, gamma, beta, out);
}

// Round 6
// 264.993 us; speedup vs baseline: 1.4622x; 1.4622x over previous
//
#include <hip/hip_runtime.h>
#include <math.h>

#define NN 100000
#define EE 1600000
#define ETOT (EE + NN)
#define NBUK 512
#define NPB 196        // nodes per bucket (512*196 >= NN)
#define CHUNK 3125     // 512*3125 == EE
#define CAP 6144       // LDS stage capacity per bucket (mean ~3332, +50 sigma)
#define GB 1563        // gemm blocks: ceil(NN/64)

typedef __attribute__((ext_vector_type(8))) short bf16x8;
typedef __attribute__((ext_vector_type(4))) float f32x4;

__device__ __forceinline__ unsigned short f2bf(float f) {
  unsigned int u = __float_as_uint(f);
  u = u + 0x7fffu + ((u >> 16) & 1u);  // RNE
  return (unsigned short)(u >> 16);
}

__device__ __forceinline__ float lrelu_exp(float e) {
  e = (e > 0.f) ? e : 0.2f * e;
  return __expf(e);
}

// Fused dispatch: blocks [0,GB) = MFMA bf16 GEMM (xwb = bf16(x @ W)) + fused
// per-(row,head) logits; blocks [GB, GB+NBUK) = P1 edge histogram (independent,
// overlaps with GEMM — hides p1's full cost and one launch gap).
__global__ __launch_bounds__(256) void k_gemm(const float* __restrict__ x,
                                              const float* __restrict__ W,
                                              const float* __restrict__ att_src,
                                              const float* __restrict__ att_dst,
                                              const int* __restrict__ ei,
                                              unsigned short* __restrict__ xwb,
                                              float* __restrict__ asrc,
                                              float* __restrict__ adst,
                                              int* __restrict__ H) {
  __shared__ __align__(16) unsigned short lds[17408];  // Wt[128][136] bf16; reused as stage[64][128]
  __shared__ float satt[256];                          // att_src[128] ++ att_dst[128]
  __shared__ int hh[NBUK];                             // p1-role histogram
  int tid = threadIdx.x;

  if (blockIdx.x >= GB) {
    // ---- P1 role: per-(chunk, bucket) histogram. H[chunk][bucket]. ----
    int j = blockIdx.x - GB;
    for (int i = tid; i < NBUK; i += 256) hh[i] = 0;
    __syncthreads();
    int e0 = j * CHUNK;
    for (int e = e0 + tid; e < e0 + CHUNK; e += 256) {
      int d = ei[(size_t)EE + e];
      atomicAdd(&hh[d / NPB], 1);
    }
    __syncthreads();
    for (int i = tid; i < NBUK; i += 256) H[j * NBUK + i] = hh[i];
    return;
  }

  // ---- GEMM role ----
  // stage W^T (bf16) : Wt[n][k], padded row stride 136 to break bank conflicts
  for (int i = tid; i < 16384; i += 256) {
    int k = i >> 7, n = i & 127;
    lds[n * 136 + k] = f2bf(W[i]);
  }
  if (tid < 128) satt[tid] = att_src[tid];
  else satt[tid] = att_dst[tid - 128];
  __syncthreads();

  int wv = tid >> 6, lane = tid & 63;
  int m = lane & 15, q = lane >> 4;
  int r = blockIdx.x * 64 + wv * 16 + m;  // this lane's A row
  bool rok = (r < NN);

  // A fragments for all 4 k-tiles: af[kt][j] = bf16(x[r][kt*32 + q*8 + j])
  bf16x8 af[4];
#pragma unroll
  for (int kt = 0; kt < 4; kt++) {
    float4 v0 = make_float4(0.f, 0.f, 0.f, 0.f), v1 = v0;
    if (rok) {
      v0 = ((const float4*)x)[(size_t)r * 32 + kt * 8 + q * 2];
      v1 = ((const float4*)x)[(size_t)r * 32 + kt * 8 + q * 2 + 1];
    }
    af[kt][0] = (short)f2bf(v0.x); af[kt][1] = (short)f2bf(v0.y);
    af[kt][2] = (short)f2bf(v0.z); af[kt][3] = (short)f2bf(v0.w);
    af[kt][4] = (short)f2bf(v1.x); af[kt][5] = (short)f2bf(v1.y);
    af[kt][6] = (short)f2bf(v1.z); af[kt][7] = (short)f2bf(v1.w);
  }

  f32x4 acc[8];
#pragma unroll
  for (int nt = 0; nt < 8; nt++) acc[nt] = (f32x4){0.f, 0.f, 0.f, 0.f};

#pragma unroll
  for (int nt = 0; nt < 8; nt++) {
#pragma unroll
    for (int kt = 0; kt < 4; kt++) {
      bf16x8 bf = *((const bf16x8*)&lds[(nt * 16 + m) * 136 + kt * 32 + q * 8]);
      acc[nt] = __builtin_amdgcn_mfma_f32_16x16x32_bf16(af[kt], bf, acc[nt], 0, 0, 0);
    }
  }

  __syncthreads();  // all waves done reading Wt; reuse LDS as output stage
#pragma unroll
  for (int nt = 0; nt < 8; nt++)
#pragma unroll
    for (int rg = 0; rg < 4; rg++)
      lds[(wv * 16 + q * 4 + rg) * 128 + nt * 16 + m] = f2bf(acc[nt][rg]);
  __syncthreads();

  size_t base = (size_t)blockIdx.x * 16384;  // bytes; block tile is contiguous
  const size_t lim = (size_t)NN * 256;
  for (int i = tid; i < 1024; i += 256) {
    size_t off = base + (size_t)i * 16;
    if (off < lim) *((uint4*)((char*)xwb + off)) = ((const uint4*)lds)[i];
  }

  // fused logits: thread t -> (row = t>>2, head = t&3); 32 channels each from LDS
  int row = tid >> 2, h = tid & 3;
  int node = blockIdx.x * 64 + row;
  if (node < NN) {
    float ss = 0.f, sd = 0.f;
#pragma unroll
    for (int cq = 0; cq < 4; cq++) {
      uint4 u = *((const uint4*)&lds[row * 128 + h * 32 + cq * 8]);
      int cb = h * 32 + cq * 8;
      float f0 = __uint_as_float(u.x << 16), f1 = __uint_as_float(u.x & 0xffff0000u);
      float f2 = __uint_as_float(u.y << 16), f3 = __uint_as_float(u.y & 0xffff0000u);
      float f4 = __uint_as_float(u.z << 16), f5 = __uint_as_float(u.z & 0xffff0000u);
      float f6 = __uint_as_float(u.w << 16), f7 = __uint_as_float(u.w & 0xffff0000u);
      ss += f0 * satt[cb] + f1 * satt[cb + 1] + f2 * satt[cb + 2] + f3 * satt[cb + 3] +
            f4 * satt[cb + 4] + f5 * satt[cb + 5] + f6 * satt[cb + 6] + f7 * satt[cb + 7];
      sd += f0 * satt[128 + cb] + f1 * satt[128 + cb + 1] + f2 * satt[128 + cb + 2] +
            f3 * satt[128 + cb + 3] + f4 * satt[128 + cb + 4] + f5 * satt[128 + cb + 5] +
            f6 * satt[128 + cb + 6] + f7 * satt[128 + cb + 7];
    }
    asrc[(size_t)node * 4 + h] = ss;
    adst[(size_t)node * 4 + h] = sd;
  }
}

// S1: per-bucket exclusive scan over chunks. R[bucket][chunk], totals T[bucket].
__global__ __launch_bounds__(512) void k_s1(const int* __restrict__ H,
                                            int* __restrict__ R, int* __restrict__ T) {
  __shared__ int s[512];
  int b = blockIdx.x, t = threadIdx.x;
  int v = H[t * NBUK + b];
  s[t] = v;
  __syncthreads();
  for (int off = 1; off < 512; off <<= 1) {
    int tmp = (t >= off) ? s[t - off] : 0;
    __syncthreads();
    s[t] += tmp;
    __syncthreads();
  }
  R[b * 512 + t] = s[t] - v;
  if (t == 511) T[b] = s[511];
}

// S2: bucket bases. BaseTmp = scan(T); Base = scan(T + nodecount(bucket)).
__global__ __launch_bounds__(512) void k_s2(const int* __restrict__ T,
                                            int* __restrict__ BaseTmp,
                                            int* __restrict__ Base) {
  __shared__ int s[512];
  __shared__ int s2[512];
  int t = threadIdx.x;
  int v = T[t];
  int ncnt = NN - t * NPB;
  ncnt = (ncnt < 0) ? 0 : ((ncnt > NPB) ? NPB : ncnt);
  int w = v + ncnt;
  s[t] = v; s2[t] = w;
  __syncthreads();
  for (int off = 1; off < 512; off <<= 1) {
    int ta = (t >= off) ? s[t - off] : 0;
    int tb = (t >= off) ? s2[t - off] : 0;
    __syncthreads();
    s[t] += ta; s2[t] += tb;
    __syncthreads();
  }
  BaseTmp[t] = s[t] - v;
  Base[t] = s2[t] - w;
}

// P3: deterministic partition by bucket; LDS cursors only. tmp word = (local_id<<17)|src.
__global__ __launch_bounds__(256) void k_p3(const int* __restrict__ ei,
                                            const int* __restrict__ R,
                                            const int* __restrict__ BaseTmp,
                                            int* __restrict__ tmpb) {
  __shared__ int cur[NBUK];
  int j = blockIdx.x, t = threadIdx.x;
  for (int b = t; b < NBUK; b += 256) cur[b] = BaseTmp[b] + R[b * 512 + j];
  __syncthreads();
  int e0 = j * CHUNK;
  for (int e = e0 + t; e < e0 + CHUNK; e += 256) {
    int s = ei[e];
    int d = ei[(size_t)EE + e];
    int b = d / NPB;
    int li = d - b * NPB;
    int pos = atomicAdd(&cur[b], 1);
    tmpb[pos] = (li << 17) | s;
  }
}

// P4: pure CSR build — one block per bucket: per-node count/scan/scatter in LDS.
__global__ __launch_bounds__(256) void k_p4(const int* __restrict__ tmpb,
                                            const int* __restrict__ T,
                                            const int* __restrict__ BaseTmp,
                                            const int* __restrict__ Base,
                                            int* __restrict__ es, int* __restrict__ offs) {
  __shared__ int cnt[256];
  __shared__ int cur[NPB];
  __shared__ int stage[CAP];
  int b = blockIdx.x, t = threadIdx.x;
  if (b == 0 && t == 0) offs[NN] = ETOT;
  int n0 = b * NPB;
  int nloc = NN - n0;
  if (nloc <= 0) return;
  if (nloc > NPB) nloc = NPB;
  int total = T[b];
  int bt = BaseTmp[b], bs = Base[b];
  cnt[t] = (t < nloc) ? 1 : 0;  // self-loop pre-counted
  __syncthreads();
  for (int e = t; e < total; e += 256) {
    int u = tmpb[bt + e];
    atomicAdd(&cnt[u >> 17], 1);
  }
  __syncthreads();
  int v = cnt[t];
  __syncthreads();
  for (int off = 1; off < 256; off <<= 1) {
    int tmp = (t >= off) ? cnt[t - off] : 0;
    __syncthreads();
    cnt[t] += tmp;
    __syncthreads();
  }
  int excl = cnt[t] - v;
  if (t < nloc) {
    offs[n0 + t] = bs + excl;
    cur[t] = excl + 1;
    if (excl < CAP) stage[excl] = n0 + t;  // self-loop src first
  }
  __syncthreads();
  for (int e = t; e < total; e += 256) {
    int u = tmpb[bt + e];
    int pos = atomicAdd(&cur[u >> 17], 1);
    if (pos < CAP) stage[pos] = u & 0x1FFFF;
  }
  __syncthreads();
  int btot = total + nloc;
  if (btot > CAP) btot = CAP;
  for (int i = t; i < btot; i += 256) es[bs + i] = stage[i];
}

// one wave per destination node: gather + on-the-fly softmax + in-register denom.
// Exp dedup: per 8-edge batch, lane l computes exp for (edge l>>3, head l&3);
// consumers fetch via __shfl(wl, q*8+h). 8 xwb gathers in flight per iter.
__global__ __launch_bounds__(256) void k_agg(const unsigned short* __restrict__ xwb,
                                             const float* __restrict__ asrc,
                                             const float* __restrict__ adst,
                                             const int* __restrict__ offs,
                                             const int* __restrict__ es,
                                             const float* __restrict__ bias,
                                             const float* __restrict__ gamma,
                                             const float* __restrict__ beta,
                                             float* __restrict__ out) {
  int lane = threadIdx.x & 63;
  int node = blockIdx.x * 4 + (threadIdx.x >> 6);
  int off0 = offs[node];
  int d = offs[node + 1] - off0;
  int h = lane >> 4;   // head for channel accumulation (c = lane*2)
  int he = lane & 3;   // head for this lane's exp duty
  int c = lane * 2;

  float4 ad4 = *((const float4*)(adst + (size_t)node * 4));
  float adh = (h & 2) ? ((h & 1) ? ad4.w : ad4.z) : ((h & 1) ? ad4.y : ad4.x);
  float ade = (he & 2) ? ((he & 1) ? ad4.w : ad4.z) : ((he & 1) ? ad4.y : ad4.x);

  const unsigned* xp = (const unsigned*)xwb + lane;
  const int* ep = es + off0;
  float ax0 = 0.f, ay0 = 0.f, ax1 = 0.f, ay1 = 0.f;
  float wsum = 0.f;

  int j = 0;
  for (; j + 8 <= d; j += 8) {
    int4 sa = *((const int4*)(ep + j));
    int4 sb = *((const int4*)(ep + j + 4));
    // lane's exp assignment: edge (lane>>3), head (lane&3); coalesced asrc read
    int se = ep[j + (lane >> 3)];
    float av = asrc[(size_t)(unsigned)se * 4u + (unsigned)he];
    unsigned u0 = xp[(unsigned)sa.x * 64u];
    unsigned u1 = xp[(unsigned)sa.y * 64u];
    unsigned u2 = xp[(unsigned)sa.z * 64u];
    unsigned u3 = xp[(unsigned)sa.w * 64u];
    unsigned u4 = xp[(unsigned)sb.x * 64u];
    unsigned u5 = xp[(unsigned)sb.y * 64u];
    unsigned u6 = xp[(unsigned)sb.z * 64u];
    unsigned u7 = xp[(unsigned)sb.w * 64u];
    float wl = lrelu_exp(av + ade);
    float w0 = __shfl(wl, 0 * 8 + h);
    float w1 = __shfl(wl, 1 * 8 + h);
    float w2 = __shfl(wl, 2 * 8 + h);
    float w3 = __shfl(wl, 3 * 8 + h);
    float w4 = __shfl(wl, 4 * 8 + h);
    float w5 = __shfl(wl, 5 * 8 + h);
    float w6 = __shfl(wl, 6 * 8 + h);
    float w7 = __shfl(wl, 7 * 8 + h);
    wsum += ((w0 + w1) + (w2 + w3)) + ((w4 + w5) + (w6 + w7));
    ax0 = fmaf(w0, __uint_as_float(u0 << 16), ax0);
    ay0 = fmaf(w0, __uint_as_float(u0 & 0xffff0000u), ay0);
    ax1 = fmaf(w1, __uint_as_float(u1 << 16), ax1);
    ay1 = fmaf(w1, __uint_as_float(u1 & 0xffff0000u), ay1);
    ax0 = fmaf(w2, __uint_as_float(u2 << 16), ax0);
    ay0 = fmaf(w2, __uint_as_float(u2 & 0xffff0000u), ay0);
    ax1 = fmaf(w3, __uint_as_float(u3 << 16), ax1);
    ay1 = fmaf(w3, __uint_as_float(u3 & 0xffff0000u), ay1);
    ax0 = fmaf(w4, __uint_as_float(u4 << 16), ax0);
    ay0 = fmaf(w4, __uint_as_float(u4 & 0xffff0000u), ay0);
    ax1 = fmaf(w5, __uint_as_float(u5 << 16), ax1);
    ay1 = fmaf(w5, __uint_as_float(u5 & 0xffff0000u), ay1);
    ax0 = fmaf(w6, __uint_as_float(u6 << 16), ax0);
    ay0 = fmaf(w6, __uint_as_float(u6 & 0xffff0000u), ay0);
    ax1 = fmaf(w7, __uint_as_float(u7 << 16), ax1);
    ay1 = fmaf(w7, __uint_as_float(u7 & 0xffff0000u), ay1);
  }
  for (; j < d; ++j) {
    int s0 = ep[j];
    float w = lrelu_exp(asrc[(size_t)(unsigned)s0 * 4u + (unsigned)h] + adh);
    wsum += w;
    unsigned u0 = xp[(unsigned)s0 * 64u];
    ax0 = fmaf(w, __uint_as_float(u0 << 16), ax0);
    ay0 = fmaf(w, __uint_as_float(u0 & 0xffff0000u), ay0);
  }
  float accx = ax0 + ax1, accy = ay0 + ay1;
  float rn = 1.f / (wsum + 1e-16f);

  float vx = accx * rn + bias[c];
  float vy = accy * rn + bias[c + 1];
  float sum = vx + vy, sq = vx * vx + vy * vy;
#pragma unroll
  for (int o = 32; o; o >>= 1) {
    sum += __shfl_xor(sum, o);
    sq += __shfl_xor(sq, o);
  }
  float mean = sum * (1.f / 128.f);
  float var = sq * (1.f / 128.f) - mean * mean;
  float rs = rsqrtf(var + 1e-5f);
  float o0 = gamma[c] * (vx - mean) * rs + beta[c];
  float o1 = gamma[c + 1] * (vy - mean) * rs + beta[c + 1];
  float2 ov; ov.x = o0; ov.y = o1;
  *((float2*)(out + (size_t)node * 128 + c)) = ov;
}

extern "C" void kernel_launch(void* const* d_in, const int* in_sizes, int n_in,
                              void* d_out, int out_size, void* d_ws, size_t ws_size,
                              hipStream_t stream) {
  const float* x = (const float*)d_in[0];
  const int* ei = (const int*)d_in[1];  // int32 per harness contract
  const float* W = (const float*)d_in[3];
  const float* att_src = (const float*)d_in[4];
  const float* att_dst = (const float*)d_in[5];
  const float* bias = (const float*)d_in[6];
  const float* gamma = (const float*)d_in[7];
  const float* beta = (const float*)d_in[8];
  float* out = (float*)d_out;

  char* p = (char*)d_ws;
  auto alloc = [&](size_t bytes) -> char* {
    char* r = p;
    p += (bytes + 255) & ~(size_t)255;
    return r;
  };
  unsigned short* xwb = (unsigned short*)alloc((size_t)NN * 128 * 2);  // 25.6 MB
  float* asrc = (float*)alloc((size_t)NN * 4 * 4);                     // 1.6 MB
  float* adst = (float*)alloc((size_t)NN * 4 * 4);                     // 1.6 MB
  int* es = (int*)alloc((size_t)ETOT * 4);                             // 6.8 MB
  int* offs = (int*)alloc((size_t)(NN + 1) * 4);
  int* tmpb = (int*)alloc((size_t)EE * 4);                             // 6.4 MB
  int* H = (int*)alloc((size_t)512 * NBUK * 4);                        // 1 MB
  int* R = (int*)alloc((size_t)NBUK * 512 * 4);                        // 1 MB
  int* T = (int*)alloc((size_t)NBUK * 4);
  int* BaseTmp = (int*)alloc((size_t)(NBUK + 1) * 4);
  int* Base = (int*)alloc((size_t)(NBUK + 1) * 4);

  k_gemm<<<GB + NBUK, 256, 0, stream>>>(x, W, att_src, att_dst, ei, xwb, asrc, adst, H);
  k_s1<<<NBUK, 512, 0, stream>>>(H, R, T);
  k_s2<<<1, 512, 0, stream>>>(T, BaseTmp, Base);
  k_p3<<<512, 256, 0, stream>>>(ei, R, BaseTmp, tmpb);
  k_p4<<<NBUK, 256, 0, stream>>>(tmpb, T, BaseTmp, Base, es, offs);
  k_agg<<<NN / 4, 256, 0, stream>>>(xwb, asrc, adst, offs, es, bias, gamma, beta, out);
}

// Round 7
// 255.185 us; speedup vs baseline: 1.5184x; 1.0384x over previous
//
#include <hip/hip_runtime.h>
#include <math.h>

#define NN 100000
#define EE 1600000
#define ETOT (EE + NN)
#define NBUK 512
#define NPB 196        // nodes per bucket (512*196 >= NN)
#define CHUNK 3125     // 512*3125 == EE
#define CAP 6144       // LDS stage capacity per bucket (mean ~3332, +50 sigma)
#define GB 1563        // gemm blocks: ceil(NN/64)

typedef __attribute__((ext_vector_type(8))) short bf16x8;
typedef __attribute__((ext_vector_type(4))) float f32x4;

__device__ __forceinline__ unsigned short f2bf(float f) {
  unsigned int u = __float_as_uint(f);
  u = u + 0x7fffu + ((u >> 16) & 1u);  // RNE
  return (unsigned short)(u >> 16);
}

__device__ __forceinline__ float lrelu_exp(float e) {
  e = (e > 0.f) ? e : 0.2f * e;
  return __expf(e);
}

// Fused dispatch: blocks [0,GB) = MFMA bf16 GEMM (xwb = bf16(x @ W)) + fused
// per-(row,head) logits; blocks [GB, GB+NBUK) = P1 edge histogram (independent,
// overlaps with GEMM — hides p1's full cost and one launch gap).
__global__ __launch_bounds__(256) void k_gemm(const float* __restrict__ x,
                                              const float* __restrict__ W,
                                              const float* __restrict__ att_src,
                                              const float* __restrict__ att_dst,
                                              const int* __restrict__ ei,
                                              unsigned short* __restrict__ xwb,
                                              float* __restrict__ asrc,
                                              float* __restrict__ adst,
                                              int* __restrict__ H) {
  __shared__ __align__(16) unsigned short lds[17408];  // Wt[128][136] bf16; reused as stage[64][128]
  __shared__ float satt[256];                          // att_src[128] ++ att_dst[128]
  __shared__ int hh[NBUK];                             // p1-role histogram
  int tid = threadIdx.x;

  if (blockIdx.x >= GB) {
    // ---- P1 role: per-(chunk, bucket) histogram. H[chunk][bucket]. ----
    int j = blockIdx.x - GB;
    for (int i = tid; i < NBUK; i += 256) hh[i] = 0;
    __syncthreads();
    int e0 = j * CHUNK;
    for (int e = e0 + tid; e < e0 + CHUNK; e += 256) {
      int d = ei[(size_t)EE + e];
      atomicAdd(&hh[d / NPB], 1);
    }
    __syncthreads();
    for (int i = tid; i < NBUK; i += 256) H[j * NBUK + i] = hh[i];
    return;
  }

  // ---- GEMM role ----
  // stage W^T (bf16) : Wt[n][k], padded row stride 136 to break bank conflicts
  for (int i = tid; i < 16384; i += 256) {
    int k = i >> 7, n = i & 127;
    lds[n * 136 + k] = f2bf(W[i]);
  }
  if (tid < 128) satt[tid] = att_src[tid];
  else satt[tid] = att_dst[tid - 128];
  __syncthreads();

  int wv = tid >> 6, lane = tid & 63;
  int m = lane & 15, q = lane >> 4;
  int r = blockIdx.x * 64 + wv * 16 + m;  // this lane's A row
  bool rok = (r < NN);

  // A fragments for all 4 k-tiles: af[kt][j] = bf16(x[r][kt*32 + q*8 + j])
  bf16x8 af[4];
#pragma unroll
  for (int kt = 0; kt < 4; kt++) {
    float4 v0 = make_float4(0.f, 0.f, 0.f, 0.f), v1 = v0;
    if (rok) {
      v0 = ((const float4*)x)[(size_t)r * 32 + kt * 8 + q * 2];
      v1 = ((const float4*)x)[(size_t)r * 32 + kt * 8 + q * 2 + 1];
    }
    af[kt][0] = (short)f2bf(v0.x); af[kt][1] = (short)f2bf(v0.y);
    af[kt][2] = (short)f2bf(v0.z); af[kt][3] = (short)f2bf(v0.w);
    af[kt][4] = (short)f2bf(v1.x); af[kt][5] = (short)f2bf(v1.y);
    af[kt][6] = (short)f2bf(v1.z); af[kt][7] = (short)f2bf(v1.w);
  }

  f32x4 acc[8];
#pragma unroll
  for (int nt = 0; nt < 8; nt++) acc[nt] = (f32x4){0.f, 0.f, 0.f, 0.f};

#pragma unroll
  for (int nt = 0; nt < 8; nt++) {
#pragma unroll
    for (int kt = 0; kt < 4; kt++) {
      bf16x8 bf = *((const bf16x8*)&lds[(nt * 16 + m) * 136 + kt * 32 + q * 8]);
      acc[nt] = __builtin_amdgcn_mfma_f32_16x16x32_bf16(af[kt], bf, acc[nt], 0, 0, 0);
    }
  }

  __syncthreads();  // all waves done reading Wt; reuse LDS as output stage
#pragma unroll
  for (int nt = 0; nt < 8; nt++)
#pragma unroll
    for (int rg = 0; rg < 4; rg++)
      lds[(wv * 16 + q * 4 + rg) * 128 + nt * 16 + m] = f2bf(acc[nt][rg]);
  __syncthreads();

  size_t base = (size_t)blockIdx.x * 16384;  // bytes; block tile is contiguous
  const size_t lim = (size_t)NN * 256;
  for (int i = tid; i < 1024; i += 256) {
    size_t off = base + (size_t)i * 16;
    if (off < lim) *((uint4*)((char*)xwb + off)) = ((const uint4*)lds)[i];
  }

  // fused logits: thread t -> (row = t>>2, head = t&3); 32 channels each from LDS
  int row = tid >> 2, h = tid & 3;
  int node = blockIdx.x * 64 + row;
  if (node < NN) {
    float ss = 0.f, sd = 0.f;
#pragma unroll
    for (int cq = 0; cq < 4; cq++) {
      uint4 u = *((const uint4*)&lds[row * 128 + h * 32 + cq * 8]);
      int cb = h * 32 + cq * 8;
      float f0 = __uint_as_float(u.x << 16), f1 = __uint_as_float(u.x & 0xffff0000u);
      float f2 = __uint_as_float(u.y << 16), f3 = __uint_as_float(u.y & 0xffff0000u);
      float f4 = __uint_as_float(u.z << 16), f5 = __uint_as_float(u.z & 0xffff0000u);
      float f6 = __uint_as_float(u.w << 16), f7 = __uint_as_float(u.w & 0xffff0000u);
      ss += f0 * satt[cb] + f1 * satt[cb + 1] + f2 * satt[cb + 2] + f3 * satt[cb + 3] +
            f4 * satt[cb + 4] + f5 * satt[cb + 5] + f6 * satt[cb + 6] + f7 * satt[cb + 7];
      sd += f0 * satt[128 + cb] + f1 * satt[128 + cb + 1] + f2 * satt[128 + cb + 2] +
            f3 * satt[128 + cb + 3] + f4 * satt[128 + cb + 4] + f5 * satt[128 + cb + 5] +
            f6 * satt[128 + cb + 6] + f7 * satt[128 + cb + 7];
    }
    asrc[(size_t)node * 4 + h] = ss;
    adst[(size_t)node * 4 + h] = sd;
  }
}

// S1: per-bucket exclusive scan over chunks. R[bucket][chunk], totals T[bucket].
__global__ __launch_bounds__(512) void k_s1(const int* __restrict__ H,
                                            int* __restrict__ R, int* __restrict__ T) {
  __shared__ int s[512];
  int b = blockIdx.x, t = threadIdx.x;
  int v = H[t * NBUK + b];
  s[t] = v;
  __syncthreads();
  for (int off = 1; off < 512; off <<= 1) {
    int tmp = (t >= off) ? s[t - off] : 0;
    __syncthreads();
    s[t] += tmp;
    __syncthreads();
  }
  R[b * 512 + t] = s[t] - v;
  if (t == 511) T[b] = s[511];
}

// S2: bucket bases. BaseTmp = scan(T); Base = scan(T + nodecount(bucket)).
__global__ __launch_bounds__(512) void k_s2(const int* __restrict__ T,
                                            int* __restrict__ BaseTmp,
                                            int* __restrict__ Base) {
  __shared__ int s[512];
  __shared__ int s2[512];
  int t = threadIdx.x;
  int v = T[t];
  int ncnt = NN - t * NPB;
  ncnt = (ncnt < 0) ? 0 : ((ncnt > NPB) ? NPB : ncnt);
  int w = v + ncnt;
  s[t] = v; s2[t] = w;
  __syncthreads();
  for (int off = 1; off < 512; off <<= 1) {
    int ta = (t >= off) ? s[t - off] : 0;
    int tb = (t >= off) ? s2[t - off] : 0;
    __syncthreads();
    s[t] += ta; s2[t] += tb;
    __syncthreads();
  }
  BaseTmp[t] = s[t] - v;
  Base[t] = s2[t] - w;
}

// P3: deterministic partition by bucket; LDS cursors only. tmp word = (local_id<<17)|src.
__global__ __launch_bounds__(256) void k_p3(const int* __restrict__ ei,
                                            const int* __restrict__ R,
                                            const int* __restrict__ BaseTmp,
                                            int* __restrict__ tmpb) {
  __shared__ int cur[NBUK];
  int j = blockIdx.x, t = threadIdx.x;
  for (int b = t; b < NBUK; b += 256) cur[b] = BaseTmp[b] + R[b * 512 + j];
  __syncthreads();
  int e0 = j * CHUNK;
  for (int e = e0 + t; e < e0 + CHUNK; e += 256) {
    int s = ei[e];
    int d = ei[(size_t)EE + e];
    int b = d / NPB;
    int li = d - b * NPB;
    int pos = atomicAdd(&cur[b], 1);
    tmpb[pos] = (li << 17) | s;
  }
}

// P4: pure CSR build — one block per bucket: per-node count/scan/scatter in LDS.
__global__ __launch_bounds__(256) void k_p4(const int* __restrict__ tmpb,
                                            const int* __restrict__ T,
                                            const int* __restrict__ BaseTmp,
                                            const int* __restrict__ Base,
                                            int* __restrict__ es, int* __restrict__ offs) {
  __shared__ int cnt[256];
  __shared__ int cur[NPB];
  __shared__ int stage[CAP];
  int b = blockIdx.x, t = threadIdx.x;
  if (b == 0 && t == 0) offs[NN] = ETOT;
  int n0 = b * NPB;
  int nloc = NN - n0;
  if (nloc <= 0) return;
  if (nloc > NPB) nloc = NPB;
  int total = T[b];
  int bt = BaseTmp[b], bs = Base[b];
  cnt[t] = (t < nloc) ? 1 : 0;  // self-loop pre-counted
  __syncthreads();
  for (int e = t; e < total; e += 256) {
    int u = tmpb[bt + e];
    atomicAdd(&cnt[u >> 17], 1);
  }
  __syncthreads();
  int v = cnt[t];
  __syncthreads();
  for (int off = 1; off < 256; off <<= 1) {
    int tmp = (t >= off) ? cnt[t - off] : 0;
    __syncthreads();
    cnt[t] += tmp;
    __syncthreads();
  }
  int excl = cnt[t] - v;
  if (t < nloc) {
    offs[n0 + t] = bs + excl;
    cur[t] = excl + 1;
    if (excl < CAP) stage[excl] = n0 + t;  // self-loop src first
  }
  __syncthreads();
  for (int e = t; e < total; e += 256) {
    int u = tmpb[bt + e];
    int pos = atomicAdd(&cur[u >> 17], 1);
    if (pos < CAP) stage[pos] = u & 0x1FFFF;
  }
  __syncthreads();
  int btot = total + nloc;
  if (btot > CAP) btot = CAP;
  for (int i = t; i < btot; i += 256) es[bs + i] = stage[i];
}

// one wave per destination node: gather + on-the-fly softmax + in-register denom.
// All batches full-width: the last batch is MASKED (out-of-range es slots clamped
// to node 0, weights zeroed) — no serial per-edge tail. One-batch-ahead es
// prefetch hides es latency under gathers; exp-duty src comes from a register
// 8-way select (sa/sb are wave-uniform), not a reload.
__global__ __launch_bounds__(256) void k_agg(const unsigned short* __restrict__ xwb,
                                             const float* __restrict__ asrc,
                                             const float* __restrict__ adst,
                                             const int* __restrict__ offs,
                                             const int* __restrict__ es,
                                             const float* __restrict__ bias,
                                             const float* __restrict__ gamma,
                                             const float* __restrict__ beta,
                                             float* __restrict__ out) {
  int lane = threadIdx.x & 63;
  int node = blockIdx.x * 4 + (threadIdx.x >> 6);
  int off0 = offs[node];
  int d = offs[node + 1] - off0;
  int h = lane >> 4;   // head for channel accumulation (c = lane*2)
  int he = lane & 3;   // head for this lane's exp duty
  int sel = lane >> 3; // this lane's exp-duty edge within a batch
  int c = lane * 2;

  float4 ad4 = *((const float4*)(adst + (size_t)node * 4));
  float ade = (he & 2) ? ((he & 1) ? ad4.w : ad4.z) : ((he & 1) ? ad4.y : ad4.x);

  const unsigned* xp = (const unsigned*)xwb + lane;
  const int* ep = es + off0;
  float ax0 = 0.f, ay0 = 0.f, ax1 = 0.f, ay1 = 0.f;
  float wsum = 0.f;

  int nb = (d + 7) >> 3;  // >= 1 (self-loop guarantees d >= 1)
  // prefetch batch 0 (row slack: es has +128 B beyond ETOT)
  int4 sa = *((const int4*)(ep));
  int4 sb = *((const int4*)(ep + 4));

  for (int b = 0; b < nb; ++b) {
    // prefetch next batch unconditionally (slack-covered; unused on last iter)
    int4 na = *((const int4*)(ep + (b + 1) * 8));
    int4 nbv = *((const int4*)(ep + (b + 1) * 8 + 4));

    int base = b * 8;
    int s0 = sa.x, s1 = sa.y, s2 = sa.z, s3 = sa.w;
    int s4 = sb.x, s5 = sb.y, s6 = sb.z, s7 = sb.w;
    bool full = (base + 8 <= d);
    if (!full) {  // wave-uniform: clamp out-of-range slots (safe gather, w=0 later)
      s0 = (base + 0 < d) ? s0 : 0; s1 = (base + 1 < d) ? s1 : 0;
      s2 = (base + 2 < d) ? s2 : 0; s3 = (base + 3 < d) ? s3 : 0;
      s4 = (base + 4 < d) ? s4 : 0; s5 = (base + 5 < d) ? s5 : 0;
      s6 = (base + 6 < d) ? s6 : 0; s7 = (base + 7 < d) ? s7 : 0;
    }
    // register 8-way select of this lane's exp-duty source (values wave-uniform)
    int t0 = (sel & 1) ? s1 : s0;
    int t1 = (sel & 1) ? s3 : s2;
    int t2 = (sel & 1) ? s5 : s4;
    int t3 = (sel & 1) ? s7 : s6;
    int p0 = (sel & 2) ? t1 : t0;
    int p1 = (sel & 2) ? t3 : t2;
    int se = (sel & 4) ? p1 : p0;
    float av = asrc[(size_t)(unsigned)se * 4u + (unsigned)he];

    unsigned u0 = xp[(unsigned)s0 * 64u];
    unsigned u1 = xp[(unsigned)s1 * 64u];
    unsigned u2 = xp[(unsigned)s2 * 64u];
    unsigned u3 = xp[(unsigned)s3 * 64u];
    unsigned u4 = xp[(unsigned)s4 * 64u];
    unsigned u5 = xp[(unsigned)s5 * 64u];
    unsigned u6 = xp[(unsigned)s6 * 64u];
    unsigned u7 = xp[(unsigned)s7 * 64u];

    float wl = lrelu_exp(av + ade);
    float w0 = __shfl(wl, 0 * 8 + h);
    float w1 = __shfl(wl, 1 * 8 + h);
    float w2 = __shfl(wl, 2 * 8 + h);
    float w3 = __shfl(wl, 3 * 8 + h);
    float w4 = __shfl(wl, 4 * 8 + h);
    float w5 = __shfl(wl, 5 * 8 + h);
    float w6 = __shfl(wl, 6 * 8 + h);
    float w7 = __shfl(wl, 7 * 8 + h);
    if (!full) {  // zero weights of padded slots
      w0 = (base + 0 < d) ? w0 : 0.f; w1 = (base + 1 < d) ? w1 : 0.f;
      w2 = (base + 2 < d) ? w2 : 0.f; w3 = (base + 3 < d) ? w3 : 0.f;
      w4 = (base + 4 < d) ? w4 : 0.f; w5 = (base + 5 < d) ? w5 : 0.f;
      w6 = (base + 6 < d) ? w6 : 0.f; w7 = (base + 7 < d) ? w7 : 0.f;
    }
    wsum += ((w0 + w1) + (w2 + w3)) + ((w4 + w5) + (w6 + w7));
    ax0 = fmaf(w0, __uint_as_float(u0 << 16), ax0);
    ay0 = fmaf(w0, __uint_as_float(u0 & 0xffff0000u), ay0);
    ax1 = fmaf(w1, __uint_as_float(u1 << 16), ax1);
    ay1 = fmaf(w1, __uint_as_float(u1 & 0xffff0000u), ay1);
    ax0 = fmaf(w2, __uint_as_float(u2 << 16), ax0);
    ay0 = fmaf(w2, __uint_as_float(u2 & 0xffff0000u), ay0);
    ax1 = fmaf(w3, __uint_as_float(u3 << 16), ax1);
    ay1 = fmaf(w3, __uint_as_float(u3 & 0xffff0000u), ay1);
    ax0 = fmaf(w4, __uint_as_float(u4 << 16), ax0);
    ay0 = fmaf(w4, __uint_as_float(u4 & 0xffff0000u), ay0);
    ax1 = fmaf(w5, __uint_as_float(u5 << 16), ax1);
    ay1 = fmaf(w5, __uint_as_float(u5 & 0xffff0000u), ay1);
    ax0 = fmaf(w6, __uint_as_float(u6 << 16), ax0);
    ay0 = fmaf(w6, __uint_as_float(u6 & 0xffff0000u), ay0);
    ax1 = fmaf(w7, __uint_as_float(u7 << 16), ax1);
    ay1 = fmaf(w7, __uint_as_float(u7 & 0xffff0000u), ay1);

    sa = na; sb = nbv;
  }

  float accx = ax0 + ax1, accy = ay0 + ay1;
  float rn = 1.f / (wsum + 1e-16f);

  float vx = accx * rn + bias[c];
  float vy = accy * rn + bias[c + 1];
  float sum = vx + vy, sq = vx * vx + vy * vy;
#pragma unroll
  for (int o = 32; o; o >>= 1) {
    sum += __shfl_xor(sum, o);
    sq += __shfl_xor(sq, o);
  }
  float mean = sum * (1.f / 128.f);
  float var = sq * (1.f / 128.f) - mean * mean;
  float rs = rsqrtf(var + 1e-5f);
  float o0 = gamma[c] * (vx - mean) * rs + beta[c];
  float o1 = gamma[c + 1] * (vy - mean) * rs + beta[c + 1];
  float2 ov; ov.x = o0; ov.y = o1;
  *((float2*)(out + (size_t)node * 128 + c)) = ov;
}

extern "C" void kernel_launch(void* const* d_in, const int* in_sizes, int n_in,
                              void* d_out, int out_size, void* d_ws, size_t ws_size,
                              hipStream_t stream) {
  const float* x = (const float*)d_in[0];
  const int* ei = (const int*)d_in[1];  // int32 per harness contract
  const float* W = (const float*)d_in[3];
  const float* att_src = (const float*)d_in[4];
  const float* att_dst = (const float*)d_in[5];
  const float* bias = (const float*)d_in[6];
  const float* gamma = (const float*)d_in[7];
  const float* beta = (const float*)d_in[8];
  float* out = (float*)d_out;

  char* p = (char*)d_ws;
  auto alloc = [&](size_t bytes) -> char* {
    char* r = p;
    p += (bytes + 255) & ~(size_t)255;
    return r;
  };
  unsigned short* xwb = (unsigned short*)alloc((size_t)NN * 128 * 2);  // 25.6 MB
  float* asrc = (float*)alloc((size_t)NN * 4 * 4);                     // 1.6 MB
  float* adst = (float*)alloc((size_t)NN * 4 * 4);                     // 1.6 MB
  int* es = (int*)alloc((size_t)ETOT * 4 + 128);                       // 6.8 MB + slack
  int* offs = (int*)alloc((size_t)(NN + 1) * 4);
  int* tmpb = (int*)alloc((size_t)EE * 4);                             // 6.4 MB
  int* H = (int*)alloc((size_t)512 * NBUK * 4);                        // 1 MB
  int* R = (int*)alloc((size_t)NBUK * 512 * 4);                        // 1 MB
  int* T = (int*)alloc((size_t)NBUK * 4);
  int* BaseTmp = (int*)alloc((size_t)(NBUK + 1) * 4);
  int* Base = (int*)alloc((size_t)(NBUK + 1) * 4);

  k_gemm<<<GB + NBUK, 256, 0, stream>>>(x, W, att_src, att_dst, ei, xwb, asrc, adst, H);
  k_s1<<<NBUK, 512, 0, stream>>>(H, R, T);
  k_s2<<<1, 512, 0, stream>>>(T, BaseTmp, Base);
  k_p3<<<512, 256, 0, stream>>>(ei, R, BaseTmp, tmpb);
  k_p4<<<NBUK, 256, 0, stream>>>(tmpb, T, BaseTmp, Base, es, offs);
  k_agg<<<NN / 4, 256, 0, stream>>>(xwb, asrc, adst, offs, es, bias, gamma, beta, out);
}